// Round 1
// baseline (537.042 us; speedup 1.0000x reference)
//
#include <hip/hip_runtime.h>
#include <hip/hip_bf16.h>
#include <math.h>

// Problem constants
#define PN 1024   // N
#define PB 4      // B
#define PC 256    // C
#define PH 8      // H
#define PD 32     // D = C/H

// ---------------------------------------------------------------------------
// Kernel 1: projection GEMM  Y = X @ W^T, X:(N*B, C), W:(C,C)
// Output written directly in (B,H,N,D) layout.
// 64x64 tile, 16x16 threads, each thread 4x4, K-step 16.
// ---------------------------------------------------------------------------
__global__ __launch_bounds__(256) void proj_kernel(
    const float* __restrict__ Xq, const float* __restrict__ Xk, const float* __restrict__ Xv,
    const float* __restrict__ Wq, const float* __restrict__ Wk, const float* __restrict__ Wv,
    float* __restrict__ Yq, float* __restrict__ Yk, float* __restrict__ Yv)
{
    const float* X; const float* W; float* Y;
    if (blockIdx.z == 0)      { X = Xq; W = Wq; Y = Yq; }
    else if (blockIdx.z == 1) { X = Xk; W = Wk; Y = Yk; }
    else                      { X = Xv; W = Wv; Y = Yv; }

    __shared__ float Xs[64][17];
    __shared__ float Ws[64][17];

    const int tid = threadIdx.x;
    const int tx = tid & 15;      // 0..15
    const int ty = tid >> 4;      // 0..15
    const int row0 = blockIdx.x * 64;
    const int col0 = blockIdx.y * 64;

    const int lr = tid >> 2;        // 0..63 (row within tile for loads)
    const int lk = (tid & 3) * 4;   // 0,4,8,12

    float acc[4][4];
    #pragma unroll
    for (int i = 0; i < 4; i++)
        #pragma unroll
        for (int j = 0; j < 4; j++) acc[i][j] = 0.f;

    for (int k0 = 0; k0 < PC; k0 += 16) {
        float4 xa = *(const float4*)&X[(size_t)(row0 + lr) * PC + k0 + lk];
        float4 wa = *(const float4*)&W[(size_t)(col0 + lr) * PC + k0 + lk];
        Xs[lr][lk + 0] = xa.x; Xs[lr][lk + 1] = xa.y; Xs[lr][lk + 2] = xa.z; Xs[lr][lk + 3] = xa.w;
        Ws[lr][lk + 0] = wa.x; Ws[lr][lk + 1] = wa.y; Ws[lr][lk + 2] = wa.z; Ws[lr][lk + 3] = wa.w;
        __syncthreads();
        #pragma unroll
        for (int kk = 0; kk < 16; kk++) {
            float a[4], b[4];
            #pragma unroll
            for (int i = 0; i < 4; i++) { a[i] = Xs[ty + 16 * i][kk]; b[i] = Ws[tx + 16 * i][kk]; }
            #pragma unroll
            for (int i = 0; i < 4; i++)
                #pragma unroll
                for (int j = 0; j < 4; j++) acc[i][j] += a[i] * b[j];
        }
        __syncthreads();
    }

    #pragma unroll
    for (int i = 0; i < 4; i++) {
        int r = row0 + ty + 16 * i;     // r = n*B + b
        int n = r >> 2, b = r & 3;
        #pragma unroll
        for (int j = 0; j < 4; j++) {
            int c = col0 + tx + 16 * j;  // c = h*D + d
            int h = c >> 5, d = c & 31;
            Y[(((size_t)(b * PH + h) << 10) + n) * PD + d] = acc[i][j];
        }
    }
}

// ---------------------------------------------------------------------------
// Kernel 2: cosine-normalize q and k rows (rows of length D=32)
// ---------------------------------------------------------------------------
__global__ __launch_bounds__(256) void norm_kernel(float* __restrict__ q, float* __restrict__ k)
{
    int gid = blockIdx.x * 256 + threadIdx.x;
    int row = gid >> 5;
    int lane = gid & 31;
    const int nrows = PB * PH * PN;   // 32768 per tensor
    float* p = (row < nrows) ? (q + (size_t)row * PD) : (k + (size_t)(row - nrows) * PD);
    float v = p[lane];
    float ss = v * v;
    #pragma unroll
    for (int off = 16; off > 0; off >>= 1) ss += __shfl_xor(ss, off, 32);
    p[lane] = v / sqrtf(ss);
}

// ---------------------------------------------------------------------------
// Kernel 3: position bias [H, N, N]
// one thread per (n, m)
// ---------------------------------------------------------------------------
__global__ __launch_bounds__(256) void bias_kernel(
    const float* __restrict__ qb, const float* __restrict__ kb,
    const float* __restrict__ pw, const float* __restrict__ pb,
    float* __restrict__ bias)
{
    int idx = blockIdx.x * 256 + threadIdx.x;
    int n = idx >> 10;
    int m = idx & 1023;

    float4 qx = ((const float4*)qb)[n];
    float4 kx = ((const float4*)kb)[m];

    float cx = 0.5f * (qx.x + qx.z), cy = 0.5f * (qx.y + qx.w);
    float w  = qx.z - qx.x + 1.0f,   hh = qx.w - qx.y + 1.0f;
    float cxr = 0.5f * (kx.x + kx.z), cyr = 0.5f * (kx.y + kx.w);
    float wr  = kx.z - kx.x + 1.0f,   hr  = kx.w - kx.y + 1.0f;

    float pm[4];
    pm[0] = logf(fabsf((cx - cxr) / w) + 1e-3f);
    pm[1] = logf(fabsf((cy - cyr) / hh) + 1e-3f);
    pm[2] = logf(w / wr);
    pm[3] = logf(hh / hr);

    // 100 / (1000^(i/8)), i=0..7
    const float inv[8] = {100.f, 42.1696503f, 17.7827941f, 7.49894209f,
                          3.16227766f, 1.33352143f, 0.562341325f, 0.237137371f};

    float emb[64];
    #pragma unroll
    for (int p = 0; p < 4; p++) {
        #pragma unroll
        for (int i = 0; i < 8; i++) {
            float s, c;
            sincosf(pm[p] * inv[i], &s, &c);
            emb[p * 16 + i]     = s;
            emb[p * 16 + 8 + i] = c;
        }
    }

    #pragma unroll
    for (int h = 0; h < PH; h++) {
        float pe = pb[h];
        #pragma unroll
        for (int c = 0; c < 64; c++) pe += emb[c] * pw[h * 64 + c];
        float bv = logf(fmaxf(pe, 0.f) + 1e-6f);
        bias[(((size_t)h << 10) + n) * PN + m] = bv;
    }
}

// ---------------------------------------------------------------------------
// Kernel 4: fused attention per (b,h): scores -> softmax -> +bias -> write attn
//           -> PV -> write out.  Block = 16 query rows of one (b,h).
// ---------------------------------------------------------------------------
#define ROWS 16
__global__ __launch_bounds__(256) void attn_kernel(
    const float* __restrict__ qn, const float* __restrict__ kn, const float* __restrict__ vp,
    const float* __restrict__ bias, float* __restrict__ out, float* __restrict__ attn_out)
{
    const int bh = blockIdx.y;          // 0..31
    const int b = bh >> 3, h = bh & 7;
    const int n0 = blockIdx.x * ROWS;
    const int tid = threadIdx.x;

    __shared__ float S[ROWS][PN];       // 64 KB
    __shared__ float qs[PD][ROWS];      // transposed q tile, 2 KB

    // load q tile transposed: qs[d][r]
    #pragma unroll
    for (int i = 0; i < 2; i++) {
        int idx = tid + i * 256;
        int r = idx >> 5, d = idx & 31;
        qs[d][r] = qn[(((size_t)bh << 10) + (n0 + r)) * PD + d];
    }
    __syncthreads();

    // ---- scores ----
    const float* kbase = kn + (((size_t)bh) << 10) * PD;
    for (int pass = 0; pass < 4; ++pass) {
        int m = pass * 256 + tid;
        float kr[32];
        const float4* kp = (const float4*)(kbase + (size_t)m * PD);
        #pragma unroll
        for (int i = 0; i < 8; i++) {
            float4 t = kp[i];
            kr[4 * i] = t.x; kr[4 * i + 1] = t.y; kr[4 * i + 2] = t.z; kr[4 * i + 3] = t.w;
        }
        float s[ROWS];
        #pragma unroll
        for (int r = 0; r < ROWS; r++) s[r] = 0.f;
        #pragma unroll
        for (int d = 0; d < PD; d++) {
            float kd = kr[d];
            float4 qa = *(const float4*)&qs[d][0];
            float4 qb4 = *(const float4*)&qs[d][4];
            float4 qc = *(const float4*)&qs[d][8];
            float4 qd4 = *(const float4*)&qs[d][12];
            s[0]  += qa.x * kd;  s[1]  += qa.y * kd;  s[2]  += qa.z * kd;  s[3]  += qa.w * kd;
            s[4]  += qb4.x * kd; s[5]  += qb4.y * kd; s[6]  += qb4.z * kd; s[7]  += qb4.w * kd;
            s[8]  += qc.x * kd;  s[9]  += qc.y * kd;  s[10] += qc.z * kd;  s[11] += qc.w * kd;
            s[12] += qd4.x * kd; s[13] += qd4.y * kd; s[14] += qd4.z * kd; s[15] += qd4.w * kd;
        }
        #pragma unroll
        for (int r = 0; r < ROWS; r++) S[r][m] = s[r];
    }
    __syncthreads();

    // ---- softmax + bias + write attn ----
    const int wave = tid >> 6, lane = tid & 63;
    for (int rr = 0; rr < 4; ++rr) {
        int r = wave * 4 + rr;
        float mx = -1e30f;
        #pragma unroll
        for (int i = 0; i < 16; i++) mx = fmaxf(mx, S[r][lane + 64 * i]);
        #pragma unroll
        for (int off = 32; off > 0; off >>= 1) mx = fmaxf(mx, __shfl_xor(mx, off, 64));

        float e[16];
        float sum = 0.f;
        #pragma unroll
        for (int i = 0; i < 16; i++) {
            e[i] = expf(S[r][lane + 64 * i] - mx);
            sum += e[i];
        }
        #pragma unroll
        for (int off = 32; off > 0; off >>= 1) sum += __shfl_xor(sum, off, 64);
        float invs = 1.f / sum;

        const float* brow = bias + (((size_t)h << 10) + (n0 + r)) * PN;
        float* arow = attn_out + (((size_t)bh << 10) + (n0 + r)) * PN;
        #pragma unroll
        for (int i = 0; i < 16; i++) {
            int m = lane + 64 * i;
            float a = e[i] * invs + brow[m];
            S[r][m] = a;
            arow[m] = a;
        }
    }
    __syncthreads();

    // ---- PV: out[b,h,n,d] = sum_m attn * v ----
    {
        const int d = tid & 31, rr = tid >> 5;   // rr: 0..7, rows rr and rr+8
        const float* vb = vp + (((size_t)bh) << 10) * PD + d;
        const float* s0 = &S[rr][0];
        const float* s1 = &S[rr + 8][0];
        float o0 = 0.f, o1 = 0.f;
        for (int k = 0; k < PN; k += 4) {
            float4 a0 = *(const float4*)&s0[k];
            float4 a1 = *(const float4*)&s1[k];
            float v0 = vb[(size_t)(k + 0) * PD];
            float v1 = vb[(size_t)(k + 1) * PD];
            float v2 = vb[(size_t)(k + 2) * PD];
            float v3 = vb[(size_t)(k + 3) * PD];
            o0 += a0.x * v0; o0 += a0.y * v1; o0 += a0.z * v2; o0 += a0.w * v3;
            o1 += a1.x * v0; o1 += a1.y * v1; o1 += a1.z * v2; o1 += a1.w * v3;
        }
        // out layout: [n, b, c] with c = h*32 + d
        out[((size_t)(n0 + rr) * PB + b) * PC + h * PD + d] = o0;
        out[((size_t)(n0 + rr + 8) * PB + b) * PC + h * PD + d] = o1;
    }
}

// ---------------------------------------------------------------------------
extern "C" void kernel_launch(void* const* d_in, const int* in_sizes, int n_in,
                              void* d_out, int out_size, void* d_ws, size_t ws_size,
                              hipStream_t stream)
{
    const float* query   = (const float*)d_in[0];
    const float* key     = (const float*)d_in[1];
    const float* value   = (const float*)d_in[2];
    const float* q_boxes = (const float*)d_in[3];
    const float* k_boxes = (const float*)d_in[4];
    const float* Wq      = (const float*)d_in[5];
    const float* Wk      = (const float*)d_in[6];
    const float* Wv      = (const float*)d_in[7];
    const float* pos_w   = (const float*)d_in[8];
    const float* pos_b   = (const float*)d_in[9];

    const size_t qkv_elems = (size_t)PB * PH * PN * PD;  // 1,048,576
    float* q_ws  = (float*)d_ws;
    float* k_ws  = q_ws + qkv_elems;
    float* v_ws  = k_ws + qkv_elems;
    float* b_ws  = v_ws + qkv_elems;                     // H*N*N = 8M floats

    float* out  = (float*)d_out;                          // [N,B,C]
    float* attn = out + (size_t)PN * PB * PC;             // [B,H,N,N]

    proj_kernel<<<dim3(64, 4, 3), 256, 0, stream>>>(query, key, value, Wq, Wk, Wv,
                                                    q_ws, k_ws, v_ws);
    norm_kernel<<<dim3(8192), 256, 0, stream>>>(q_ws, k_ws);
    bias_kernel<<<dim3(4096), 256, 0, stream>>>(q_boxes, k_boxes, pos_w, pos_b, b_ws);
    attn_kernel<<<dim3(PN / ROWS, PB * PH), 256, 0, stream>>>(q_ws, k_ws, v_ws, b_ws,
                                                              out, attn);
}

// Round 4
// 256.608 us; speedup vs baseline: 2.0928x; 2.0928x over previous
//
#include <hip/hip_runtime.h>
#include <hip/hip_bf16.h>
#include <math.h>

#define PN 1024
#define PB 4
#define PC 256
#define PH 8
#define PD 32

typedef __attribute__((ext_vector_type(8))) short bf16x8;
typedef __attribute__((ext_vector_type(4))) float f32x4;

__device__ __forceinline__ unsigned short f2b(float f) {
    unsigned int u = __builtin_bit_cast(unsigned int, f);
    unsigned int r = (u + 0x7fffu + ((u >> 16) & 1u)) >> 16;
    return (unsigned short)r;
}
__device__ __forceinline__ float b2f(unsigned short u) {
    return __builtin_bit_cast(float, ((unsigned int)u) << 16);
}

// ---------------------------------------------------------------------------
// Kernel 0: f32 -> bf16 conversion of X (query,key,value) and W (Wq,Wk,Wv)
// ---------------------------------------------------------------------------
__global__ __launch_bounds__(256) void cvt_kernel(
    const float* __restrict__ q, const float* __restrict__ k, const float* __restrict__ v,
    const float* __restrict__ wq, const float* __restrict__ wk, const float* __restrict__ wv,
    unsigned short* __restrict__ xq, unsigned short* __restrict__ xk, unsigned short* __restrict__ xv,
    unsigned short* __restrict__ wqb, unsigned short* __restrict__ wkb, unsigned short* __restrict__ wvb)
{
    int g = blockIdx.x * 256 + threadIdx.x;   // float4 groups; total 835584
    const float* src; unsigned short* dst; int off;
    if (g < 262144)      { src = q; dst = xq; off = g; }
    else if (g < 524288) { src = k; dst = xk; off = g - 262144; }
    else if (g < 786432) { src = v; dst = xv; off = g - 524288; }
    else {
        int r = g - 786432; int t = r >> 14; off = r & 16383;
        src = (t == 0) ? wq : (t == 1) ? wk : wv;
        dst = (t == 0) ? wqb : (t == 1) ? wkb : wvb;
    }
    float4 f = ((const float4*)src)[off];
    ushort4 o; o.x = f2b(f.x); o.y = f2b(f.y); o.z = f2b(f.z); o.w = f2b(f.w);
    ((ushort4*)dst)[off] = o;
}

// ---------------------------------------------------------------------------
// Kernel 1: projection via MFMA.  Y = X @ W^T  (X: 4096x256 bf16, W: 256x256)
// z=0: q -> qb [bh][n][d] bf16 (unnormalized)
// z=1: k -> kb [bh][n][d] bf16 (unnormalized)
// z=2: v -> vt [bh][d][n] bf16 (transposed)
// ---------------------------------------------------------------------------
__global__ __launch_bounds__(256) void proj_mfma(
    const unsigned short* __restrict__ xq, const unsigned short* __restrict__ xk, const unsigned short* __restrict__ xv,
    const unsigned short* __restrict__ wq, const unsigned short* __restrict__ wk, const unsigned short* __restrict__ wv,
    unsigned short* __restrict__ qb, unsigned short* __restrict__ kb, unsigned short* __restrict__ vt)
{
    const int z = blockIdx.z;
    const unsigned short* X = (z == 0) ? xq : (z == 1) ? xk : xv;
    const unsigned short* W = (z == 0) ? wq : (z == 1) ? wk : wv;

    const int row0 = blockIdx.x * 64, col0 = blockIdx.y * 64;
    const int tid = threadIdx.x;
    const int w = tid >> 6, l = tid & 63;
    const int l15 = l & 15, lg = l >> 4;
    const int wm = w >> 1, wn = w & 1;

    f32x4 acc[2][2];
    #pragma unroll
    for (int a = 0; a < 2; a++)
        #pragma unroll
        for (int b = 0; b < 2; b++) acc[a][b] = (f32x4){0.f, 0.f, 0.f, 0.f};

    #pragma unroll
    for (int ks = 0; ks < 8; ks++) {
        int koff = ks * 32 + lg * 8;
        bf16x8 a0 = *(const bf16x8*)(X + (size_t)(row0 + wm * 32 + l15) * 256 + koff);
        bf16x8 a1 = *(const bf16x8*)(X + (size_t)(row0 + wm * 32 + 16 + l15) * 256 + koff);
        bf16x8 b0 = *(const bf16x8*)(W + (size_t)(col0 + wn * 32 + l15) * 256 + koff);
        bf16x8 b1 = *(const bf16x8*)(W + (size_t)(col0 + wn * 32 + 16 + l15) * 256 + koff);
        acc[0][0] = __builtin_amdgcn_mfma_f32_16x16x32_bf16(a0, b0, acc[0][0], 0, 0, 0);
        acc[0][1] = __builtin_amdgcn_mfma_f32_16x16x32_bf16(a0, b1, acc[0][1], 0, 0, 0);
        acc[1][0] = __builtin_amdgcn_mfma_f32_16x16x32_bf16(a1, b0, acc[1][0], 0, 0, 0);
        acc[1][1] = __builtin_amdgcn_mfma_f32_16x16x32_bf16(a1, b1, acc[1][1], 0, 0, 0);
    }

    #pragma unroll
    for (int as = 0; as < 2; as++) {
        #pragma unroll
        for (int bs = 0; bs < 2; bs++) {
            #pragma unroll
            for (int r = 0; r < 4; r++) {
                int Xrow = row0 + wm * 32 + as * 16 + lg * 4 + r;
                int c = col0 + wn * 32 + bs * 16 + l15;
                int n = Xrow >> 2, bb = Xrow & 3, hh = c >> 5, dd = c & 31;
                unsigned short val = f2b(acc[as][bs][r]);
                if (z == 0)      qb[((size_t)((bb * 8 + hh) * 1024 + n)) * 32 + dd] = val;
                else if (z == 1) kb[((size_t)((bb * 8 + hh) * 1024 + n)) * 32 + dd] = val;
                else             vt[((size_t)((bb * 8 + hh) * 32 + dd)) * 1024 + n] = val;
            }
        }
    }
}

// ---------------------------------------------------------------------------
// Kernel 2: in-place cosine normalization of qb, kb rows (32 bf16 each)
// one thread per row
// ---------------------------------------------------------------------------
__global__ __launch_bounds__(256) void norm_kernel(unsigned short* __restrict__ qb,
                                                   unsigned short* __restrict__ kb)
{
    int idx = blockIdx.x * 256 + threadIdx.x;   // 0..65535
    unsigned short* p = (idx < 32768) ? qb + (size_t)idx * 32
                                      : kb + (size_t)(idx - 32768) * 32;
    const unsigned int* pu = (const unsigned int*)p;
    float g[32]; float s2 = 0.f;
    #pragma unroll
    for (int j = 0; j < 16; j++) {
        unsigned int u = pu[j];
        g[2 * j]     = b2f((unsigned short)(u & 0xffff));
        g[2 * j + 1] = b2f((unsigned short)(u >> 16));
        s2 += g[2 * j] * g[2 * j] + g[2 * j + 1] * g[2 * j + 1];
    }
    float inv = rsqrtf(s2);
    unsigned int* po = (unsigned int*)p;
    #pragma unroll
    for (int j = 0; j < 16; j++) {
        unsigned int lo = f2b(g[2 * j] * inv);
        unsigned int hi = f2b(g[2 * j + 1] * inv);
        po[j] = lo | (hi << 16);
    }
}

// ---------------------------------------------------------------------------
// Kernel 3: position bias [H,N,N] -> bf16
// ---------------------------------------------------------------------------
__global__ __launch_bounds__(256) void bias_kernel(
    const float* __restrict__ qbx, const float* __restrict__ kbx,
    const float* __restrict__ pw, const float* __restrict__ pb,
    unsigned short* __restrict__ biasb)
{
    __shared__ float4 pwS[128];
    __shared__ float pbS[8];
    int tid = threadIdx.x;
    if (tid < 128) pwS[tid] = ((const float4*)pw)[tid];
    if (tid < 8) pbS[tid] = pb[tid];
    __syncthreads();

    int idx = blockIdx.x * 256 + tid;
    int n = idx >> 10, m = idx & 1023;

    float4 qx = ((const float4*)qbx)[n];
    float4 kx = ((const float4*)kbx)[m];

    float cx = 0.5f * (qx.x + qx.z), cy = 0.5f * (qx.y + qx.w);
    float w  = qx.z - qx.x + 1.0f,   hh = qx.w - qx.y + 1.0f;
    float cxr = 0.5f * (kx.x + kx.z), cyr = 0.5f * (kx.y + kx.w);
    float wr  = kx.z - kx.x + 1.0f,   hr  = kx.w - kx.y + 1.0f;

    float pm[4];
    pm[0] = logf(fabsf((cx - cxr) / w) + 1e-3f);
    pm[1] = logf(fabsf((cy - cyr) / hh) + 1e-3f);
    pm[2] = logf(w / wr);
    pm[3] = logf(hh / hr);

    const float inv[8] = {100.f, 42.1696503f, 17.7827941f, 7.49894209f,
                          3.16227766f, 1.33352143f, 0.562341325f, 0.237137371f};

    float emb[64];
    #pragma unroll
    for (int p = 0; p < 4; p++) {
        #pragma unroll
        for (int i = 0; i < 8; i++) {
            float s, c;
            sincosf(pm[p] * inv[i], &s, &c);
            emb[p * 16 + i]     = s;
            emb[p * 16 + 8 + i] = c;
        }
    }

    #pragma unroll
    for (int h = 0; h < PH; h++) {
        float acc = pbS[h];
        #pragma unroll
        for (int c4 = 0; c4 < 16; c4++) {
            float4 w4 = pwS[h * 16 + c4];
            acc += emb[c4 * 4 + 0] * w4.x + emb[c4 * 4 + 1] * w4.y
                 + emb[c4 * 4 + 2] * w4.z + emb[c4 * 4 + 3] * w4.w;
        }
        float bv = __logf(fmaxf(acc, 0.f) + 1e-6f);
        biasb[((size_t)(h * 1024 + n)) * 1024 + m] = f2b(bv);
    }
}

// ---------------------------------------------------------------------------
// Kernel 4: fused attention, MFMA.  Block: 32 queries x 1024 keys of one (b,h).
// 512 threads = 8 waves.
// ---------------------------------------------------------------------------
#define SBS 1032   // bf16 elems per Sb row: 2064 B (16B aligned, ~2-way banks)

__global__ __launch_bounds__(512, 4) void attn_kernel(
    const unsigned short* __restrict__ qb, const unsigned short* __restrict__ kb,
    const unsigned short* __restrict__ vt, const unsigned short* __restrict__ biasb,
    float* __restrict__ out, float* __restrict__ attn_out)
{
    __shared__ unsigned short Sb[32][SBS];        // 66048 B
    __shared__ float part[8][16][17];             // 8704 B

    const int bh = blockIdx.y;
    const int b = bh >> 3, h = bh & 7;
    const int n0 = blockIdx.x * 32;
    const int tid = threadIdx.x;
    const int w = tid >> 6, l = tid & 63;
    const int l15 = l & 15, lg = l >> 4;

    // ---- QK^T: wave (wq,wk) does 16 queries x 256 keys = 16 MFMAs ----
    {
        const int wq = w >> 2, wk = w & 3;
        const int qrow = n0 + wq * 16 + l15;
        bf16x8 aq = *(const bf16x8*)(qb + ((size_t)(bh << 10) + qrow) * 32 + lg * 8);
        #pragma unroll 4
        for (int t = 0; t < 16; ++t) {
            int key = wk * 256 + t * 16 + l15;
            bf16x8 bk = *(const bf16x8*)(kb + ((size_t)(bh << 10) + key) * 32 + lg * 8);
            f32x4 acc = (f32x4){0.f, 0.f, 0.f, 0.f};
            acc = __builtin_amdgcn_mfma_f32_16x16x32_bf16(aq, bk, acc, 0, 0, 0);
            int colb = wk * 256 + t * 16 + l15;
            #pragma unroll
            for (int r = 0; r < 4; ++r)
                Sb[wq * 16 + lg * 4 + r][colb] = f2b(acc[r]);
        }
    }
    __syncthreads();

    // ---- softmax + bias + attn write + P(bf16) back to LDS ----
    {
        for (int rr = 0; rr < 4; ++rr) {
            int r = w * 4 + rr;
            float s[16];
            #pragma unroll
            for (int i = 0; i < 16; ++i) s[i] = b2f(Sb[r][l + 64 * i]);
            float mx = s[0];
            #pragma unroll
            for (int i = 1; i < 16; ++i) mx = fmaxf(mx, s[i]);
            #pragma unroll
            for (int off = 32; off > 0; off >>= 1) mx = fmaxf(mx, __shfl_xor(mx, off));
            float e[16], sum = 0.f;
            #pragma unroll
            for (int i = 0; i < 16; ++i) { e[i] = __expf(s[i] - mx); sum += e[i]; }
            #pragma unroll
            for (int off = 32; off > 0; off >>= 1) sum += __shfl_xor(sum, off);
            float invs = 1.f / sum;

            const unsigned short* brow = biasb + ((size_t)(h * 1024 + n0 + r)) * 1024;
            float* arow = attn_out + ((size_t)(bh * 1024 + n0 + r)) * 1024;
            #pragma unroll
            for (int i = 0; i < 16; ++i) {
                int m = l + 64 * i;
                float a = e[i] * invs + b2f(brow[m]);
                arow[m] = a;
                Sb[r][m] = f2b(a);
            }
        }
    }
    __syncthreads();

    // ---- PV: wave = (tile, khalf); tile = (qs, ds) of 16x16 out ----
    {
        const int tile = w >> 1, kh = w & 1;
        const int qs = tile >> 1, ds = tile & 1;
        f32x4 acc = (f32x4){0.f, 0.f, 0.f, 0.f};
        const unsigned short* vrow = vt + ((size_t)(bh * 32 + ds * 16 + l15) << 10);
        const unsigned short* srow = &Sb[qs * 16 + l15][0];
        #pragma unroll 4
        for (int st = 0; st < 16; ++st) {
            int m0 = kh * 512 + st * 32 + lg * 8;
            bf16x8 ap = *(const bf16x8*)(srow + m0);
            bf16x8 bv = *(const bf16x8*)(vrow + m0);
            acc = __builtin_amdgcn_mfma_f32_16x16x32_bf16(ap, bv, acc, 0, 0, 0);
        }
        #pragma unroll
        for (int r = 0; r < 4; ++r) part[w][lg * 4 + r][l15] = acc[r];
    }
    __syncthreads();

    // ---- reduce k-halves, write out [n][b][c] ----
    {
        #pragma unroll
        for (int e = 0; e < 2; ++e) {
            int idx = tid + e * 512;
            int q = idx >> 5, d = idx & 31;
            int w0 = ((q >> 4) * 2 + (d >> 4)) << 1;
            float v = part[w0][q & 15][d & 15] + part[w0 + 1][q & 15][d & 15];
            out[((size_t)(n0 + q) * PB + b) * PC + h * PD + d] = v;
        }
    }
}

// ---------------------------------------------------------------------------
extern "C" void kernel_launch(void* const* d_in, const int* in_sizes, int n_in,
                              void* d_out, int out_size, void* d_ws, size_t ws_size,
                              hipStream_t stream)
{
    const float* query   = (const float*)d_in[0];
    const float* key     = (const float*)d_in[1];
    const float* value   = (const float*)d_in[2];
    const float* q_boxes = (const float*)d_in[3];
    const float* k_boxes = (const float*)d_in[4];
    const float* Wq      = (const float*)d_in[5];
    const float* Wk      = (const float*)d_in[6];
    const float* Wv      = (const float*)d_in[7];
    const float* pos_w   = (const float*)d_in[8];
    const float* pos_b   = (const float*)d_in[9];

    unsigned short* u = (unsigned short*)d_ws;
    unsigned short* xq  = u;                      // 1048576
    unsigned short* xk  = xq + 1048576;
    unsigned short* xv  = xk + 1048576;
    unsigned short* wqb = xv + 1048576;           // 65536 each
    unsigned short* wkb = wqb + 65536;
    unsigned short* wvb = wkb + 65536;
    unsigned short* qbf = wvb + 65536;            // 1048576 [bh][n][d]
    unsigned short* kbf = qbf + 1048576;
    unsigned short* vtb = kbf + 1048576;          // [bh][d][n]
    unsigned short* bias = vtb + 1048576;         // 8388608

    float* out  = (float*)d_out;                  // [N,B,C]
    float* attn = out + (size_t)PN * PB * PC;     // [B,H,N,N]

    cvt_kernel<<<dim3(3264), 256, 0, stream>>>(query, key, value, Wq, Wk, Wv,
                                               xq, xk, xv, wqb, wkb, wvb);
    proj_mfma<<<dim3(64, 4, 3), 256, 0, stream>>>(xq, xk, xv, wqb, wkb, wvb,
                                                  qbf, kbf, vtb);
    norm_kernel<<<dim3(256), 256, 0, stream>>>(qbf, kbf);
    bias_kernel<<<dim3(4096), 256, 0, stream>>>(q_boxes, k_boxes, pos_w, pos_b, bias);
    attn_kernel<<<dim3(32, 32), 512, 0, stream>>>(qbf, kbf, vtb, bias, out, attn);
}

// Round 6
// 235.449 us; speedup vs baseline: 2.2809x; 1.0899x over previous
//
#include <hip/hip_runtime.h>
#include <hip/hip_bf16.h>
#include <math.h>

#define PN 1024
#define PB 4
#define PC 256
#define PH 8
#define PD 32

typedef __attribute__((ext_vector_type(8))) short bf16x8;
typedef __attribute__((ext_vector_type(4))) float f32x4;

__device__ __forceinline__ unsigned short f2b(float f) {
    unsigned int u = __builtin_bit_cast(unsigned int, f);
    unsigned int r = (u + 0x7fffu + ((u >> 16) & 1u)) >> 16;
    return (unsigned short)r;
}
__device__ __forceinline__ float b2f(unsigned short u) {
    return __builtin_bit_cast(float, ((unsigned int)u) << 16);
}

// ---------------------------------------------------------------------------
// Kernel 0: f32 -> bf16 conversion of X (query,key,value) and W (Wq,Wk,Wv)
// ---------------------------------------------------------------------------
__global__ __launch_bounds__(256) void cvt_kernel(
    const float* __restrict__ q, const float* __restrict__ k, const float* __restrict__ v,
    const float* __restrict__ wq, const float* __restrict__ wk, const float* __restrict__ wv,
    unsigned short* __restrict__ xq, unsigned short* __restrict__ xk, unsigned short* __restrict__ xv,
    unsigned short* __restrict__ wqb, unsigned short* __restrict__ wkb, unsigned short* __restrict__ wvb)
{
    int g = blockIdx.x * 256 + threadIdx.x;   // float4 groups; total 835584
    const float* src; unsigned short* dst; int off;
    if (g < 262144)      { src = q; dst = xq; off = g; }
    else if (g < 524288) { src = k; dst = xk; off = g - 262144; }
    else if (g < 786432) { src = v; dst = xv; off = g - 524288; }
    else {
        int r = g - 786432; int t = r >> 14; off = r & 16383;
        src = (t == 0) ? wq : (t == 1) ? wk : wv;
        dst = (t == 0) ? wqb : (t == 1) ? wkb : wvb;
    }
    float4 f = ((const float4*)src)[off];
    ushort4 o; o.x = f2b(f.x); o.y = f2b(f.y); o.z = f2b(f.z); o.w = f2b(f.w);
    ((ushort4*)dst)[off] = o;
}

// ---------------------------------------------------------------------------
// Kernel 1: projection via MFMA.  Y = X @ W^T  (X: 4096x256 bf16, W: 256x256)
// z=0: q -> qb [bh][n][d] bf16 (unnormalized)
// z=1: k -> kb [bh][n][d] bf16 (unnormalized)
// z=2: v -> vt [bh][d][n] bf16 (transposed)
// ---------------------------------------------------------------------------
__global__ __launch_bounds__(256) void proj_mfma(
    const unsigned short* __restrict__ xq, const unsigned short* __restrict__ xk, const unsigned short* __restrict__ xv,
    const unsigned short* __restrict__ wq, const unsigned short* __restrict__ wk, const unsigned short* __restrict__ wv,
    unsigned short* __restrict__ qb, unsigned short* __restrict__ kb, unsigned short* __restrict__ vt)
{
    const int z = blockIdx.z;
    const unsigned short* X = (z == 0) ? xq : (z == 1) ? xk : xv;
    const unsigned short* W = (z == 0) ? wq : (z == 1) ? wk : wv;

    const int row0 = blockIdx.x * 64, col0 = blockIdx.y * 64;
    const int tid = threadIdx.x;
    const int w = tid >> 6, l = tid & 63;
    const int l15 = l & 15, lg = l >> 4;
    const int wm = w >> 1, wn = w & 1;

    f32x4 acc[2][2];
    #pragma unroll
    for (int a = 0; a < 2; a++)
        #pragma unroll
        for (int b = 0; b < 2; b++) acc[a][b] = (f32x4){0.f, 0.f, 0.f, 0.f};

    #pragma unroll
    for (int ks = 0; ks < 8; ks++) {
        int koff = ks * 32 + lg * 8;
        bf16x8 a0 = *(const bf16x8*)(X + (size_t)(row0 + wm * 32 + l15) * 256 + koff);
        bf16x8 a1 = *(const bf16x8*)(X + (size_t)(row0 + wm * 32 + 16 + l15) * 256 + koff);
        bf16x8 b0 = *(const bf16x8*)(W + (size_t)(col0 + wn * 32 + l15) * 256 + koff);
        bf16x8 b1 = *(const bf16x8*)(W + (size_t)(col0 + wn * 32 + 16 + l15) * 256 + koff);
        acc[0][0] = __builtin_amdgcn_mfma_f32_16x16x32_bf16(a0, b0, acc[0][0], 0, 0, 0);
        acc[0][1] = __builtin_amdgcn_mfma_f32_16x16x32_bf16(a0, b1, acc[0][1], 0, 0, 0);
        acc[1][0] = __builtin_amdgcn_mfma_f32_16x16x32_bf16(a1, b0, acc[1][0], 0, 0, 0);
        acc[1][1] = __builtin_amdgcn_mfma_f32_16x16x32_bf16(a1, b1, acc[1][1], 0, 0, 0);
    }

    #pragma unroll
    for (int as = 0; as < 2; as++) {
        #pragma unroll
        for (int bs = 0; bs < 2; bs++) {
            #pragma unroll
            for (int r = 0; r < 4; r++) {
                int Xrow = row0 + wm * 32 + as * 16 + lg * 4 + r;
                int c = col0 + wn * 32 + bs * 16 + l15;
                int n = Xrow >> 2, bb = Xrow & 3, hh = c >> 5, dd = c & 31;
                unsigned short val = f2b(acc[as][bs][r]);
                if (z == 0)      qb[((size_t)((bb * 8 + hh) * 1024 + n)) * 32 + dd] = val;
                else if (z == 1) kb[((size_t)((bb * 8 + hh) * 1024 + n)) * 32 + dd] = val;
                else             vt[((size_t)((bb * 8 + hh) * 32 + dd)) * 1024 + n] = val;
            }
        }
    }
}

// ---------------------------------------------------------------------------
// Kernel 2: in-place cosine normalization of qb, kb rows (32 bf16 each)
// one thread per row
// ---------------------------------------------------------------------------
__global__ __launch_bounds__(256) void norm_kernel(unsigned short* __restrict__ qb,
                                                   unsigned short* __restrict__ kb)
{
    int idx = blockIdx.x * 256 + threadIdx.x;   // 0..65535
    unsigned short* p = (idx < 32768) ? qb + (size_t)idx * 32
                                      : kb + (size_t)(idx - 32768) * 32;
    const unsigned int* pu = (const unsigned int*)p;
    float g[32]; float s2 = 0.f;
    #pragma unroll
    for (int j = 0; j < 16; j++) {
        unsigned int u = pu[j];
        g[2 * j]     = b2f((unsigned short)(u & 0xffff));
        g[2 * j + 1] = b2f((unsigned short)(u >> 16));
        s2 += g[2 * j] * g[2 * j] + g[2 * j + 1] * g[2 * j + 1];
    }
    float inv = rsqrtf(s2);
    unsigned int* po = (unsigned int*)p;
    #pragma unroll
    for (int j = 0; j < 16; j++) {
        unsigned int lo = f2b(g[2 * j] * inv);
        unsigned int hi = f2b(g[2 * j + 1] * inv);
        po[j] = lo | (hi << 16);
    }
}

// ---------------------------------------------------------------------------
// Kernel 3: position bias [H,N,N] -> bf16
// hw sin/cos: args bounded (|pm|*100 <= ~650 rad ~ 103 rev, inside v_sin domain)
// ---------------------------------------------------------------------------
__global__ __launch_bounds__(256) void bias_kernel(
    const float* __restrict__ qbx, const float* __restrict__ kbx,
    const float* __restrict__ pw, const float* __restrict__ pb,
    unsigned short* __restrict__ biasb)
{
    __shared__ float4 pwS[128];
    __shared__ float pbS[8];
    int tid = threadIdx.x;
    if (tid < 128) pwS[tid] = ((const float4*)pw)[tid];
    if (tid < 8) pbS[tid] = pb[tid];
    __syncthreads();

    int idx = blockIdx.x * 256 + tid;
    int n = idx >> 10, m = idx & 1023;

    float4 qx = ((const float4*)qbx)[n];
    float4 kx = ((const float4*)kbx)[m];

    float cx = 0.5f * (qx.x + qx.z), cy = 0.5f * (qx.y + qx.w);
    float w  = qx.z - qx.x + 1.0f,   hh = qx.w - qx.y + 1.0f;
    float cxr = 0.5f * (kx.x + kx.z), cyr = 0.5f * (kx.y + kx.w);
    float wr  = kx.z - kx.x + 1.0f,   hr  = kx.w - kx.y + 1.0f;

    float pm[4];
    pm[0] = __logf(fabsf((cx - cxr) / w) + 1e-3f);
    pm[1] = __logf(fabsf((cy - cyr) / hh) + 1e-3f);
    pm[2] = __logf(w / wr);
    pm[3] = __logf(hh / hr);

    const float inv[8] = {100.f, 42.1696503f, 17.7827941f, 7.49894209f,
                          3.16227766f, 1.33352143f, 0.562341325f, 0.237137371f};

    float emb[64];
    #pragma unroll
    for (int p = 0; p < 4; p++) {
        #pragma unroll
        for (int i = 0; i < 8; i++) {
            float a = pm[p] * inv[i];
            emb[p * 16 + i]     = __sinf(a);   // v_mul + v_sin_f32
            emb[p * 16 + 8 + i] = __cosf(a);   // v_mul + v_cos_f32
        }
    }

    #pragma unroll
    for (int h = 0; h < PH; h++) {
        float acc = pbS[h];
        #pragma unroll
        for (int c4 = 0; c4 < 16; c4++) {
            float4 w4 = pwS[h * 16 + c4];
            acc += emb[c4 * 4 + 0] * w4.x + emb[c4 * 4 + 1] * w4.y
                 + emb[c4 * 4 + 2] * w4.z + emb[c4 * 4 + 3] * w4.w;
        }
        float bv = __logf(fmaxf(acc, 0.f) + 1e-6f);
        biasb[((size_t)(h * 1024 + n)) * 1024 + m] = f2b(bv);
    }
}

// ---------------------------------------------------------------------------
// Kernel 4: fused attention, MFMA.  Block: 32 queries x 1024 keys of one (b,h).
// 512 threads = 8 waves.
// ---------------------------------------------------------------------------
#define SBS 1032   // bf16 elems per Sb row: 2064 B (16B aligned, ~2-way banks)

__global__ __launch_bounds__(512, 4) void attn_kernel(
    const unsigned short* __restrict__ qb, const unsigned short* __restrict__ kb,
    const unsigned short* __restrict__ vt, const unsigned short* __restrict__ biasb,
    float* __restrict__ out, float* __restrict__ attn_out)
{
    __shared__ unsigned short Sb[32][SBS];        // 66048 B
    __shared__ float part[8][16][17];             // 8704 B

    const int bh = blockIdx.y;
    const int b = bh >> 3, h = bh & 7;
    const int n0 = blockIdx.x * 32;
    const int tid = threadIdx.x;
    const int w = tid >> 6, l = tid & 63;
    const int l15 = l & 15, lg = l >> 4;

    // ---- QK^T: wave (wq,wk) does 16 queries x 256 keys = 16 MFMAs ----
    {
        const int wq = w >> 2, wk = w & 3;
        const int qrow = n0 + wq * 16 + l15;
        bf16x8 aq = *(const bf16x8*)(qb + ((size_t)(bh << 10) + qrow) * 32 + lg * 8);
        #pragma unroll 4
        for (int t = 0; t < 16; ++t) {
            int key = wk * 256 + t * 16 + l15;
            bf16x8 bk = *(const bf16x8*)(kb + ((size_t)(bh << 10) + key) * 32 + lg * 8);
            f32x4 acc = (f32x4){0.f, 0.f, 0.f, 0.f};
            acc = __builtin_amdgcn_mfma_f32_16x16x32_bf16(aq, bk, acc, 0, 0, 0);
            int colb = wk * 256 + t * 16 + l15;
            #pragma unroll
            for (int r = 0; r < 4; ++r)
                Sb[wq * 16 + lg * 4 + r][colb] = f2b(acc[r]);
        }
    }
    __syncthreads();

    // ---- softmax + bias + attn write + P(bf16) back to LDS ----
    {
        for (int rr = 0; rr < 4; ++rr) {
            int r = w * 4 + rr;
            float s[16];
            #pragma unroll
            for (int i = 0; i < 16; ++i) s[i] = b2f(Sb[r][l + 64 * i]);
            float mx = s[0];
            #pragma unroll
            for (int i = 1; i < 16; ++i) mx = fmaxf(mx, s[i]);
            #pragma unroll
            for (int off = 32; off > 0; off >>= 1) mx = fmaxf(mx, __shfl_xor(mx, off));
            float e[16], sum = 0.f;
            #pragma unroll
            for (int i = 0; i < 16; ++i) { e[i] = __expf(s[i] - mx); sum += e[i]; }
            #pragma unroll
            for (int off = 32; off > 0; off >>= 1) sum += __shfl_xor(sum, off);
            float invs = 1.f / sum;

            const unsigned short* brow = biasb + ((size_t)(h * 1024 + n0 + r)) * 1024;
            float* arow = attn_out + ((size_t)(bh * 1024 + n0 + r)) * 1024;
            #pragma unroll
            for (int i = 0; i < 16; ++i) {
                int m = l + 64 * i;
                float a = e[i] * invs + b2f(brow[m]);
                arow[m] = a;
                Sb[r][m] = f2b(a);
            }
        }
    }
    __syncthreads();

    // ---- PV: wave = (tile, khalf); tile = (qs, ds) of 16x16 out ----
    {
        const int tile = w >> 1, kh = w & 1;
        const int qs = tile >> 1, ds = tile & 1;
        f32x4 acc = (f32x4){0.f, 0.f, 0.f, 0.f};
        const unsigned short* vrow = vt + ((size_t)(bh * 32 + ds * 16 + l15) << 10);
        const unsigned short* srow = &Sb[qs * 16 + l15][0];
        #pragma unroll 4
        for (int st = 0; st < 16; ++st) {
            int m0 = kh * 512 + st * 32 + lg * 8;
            bf16x8 ap = *(const bf16x8*)(srow + m0);
            bf16x8 bv = *(const bf16x8*)(vrow + m0);
            acc = __builtin_amdgcn_mfma_f32_16x16x32_bf16(ap, bv, acc, 0, 0, 0);
        }
        #pragma unroll
        for (int r = 0; r < 4; ++r) part[w][lg * 4 + r][l15] = acc[r];
    }
    __syncthreads();

    // ---- reduce k-halves, write out [n][b][c] ----
    {
        #pragma unroll
        for (int e = 0; e < 2; ++e) {
            int idx = tid + e * 512;
            int q = idx >> 5, d = idx & 31;
            int w0 = ((q >> 4) * 2 + (d >> 4)) << 1;
            float v = part[w0][q & 15][d & 15] + part[w0 + 1][q & 15][d & 15];
            out[((size_t)(n0 + q) * PB + b) * PC + h * PD + d] = v;
        }
    }
}

// ---------------------------------------------------------------------------
extern "C" void kernel_launch(void* const* d_in, const int* in_sizes, int n_in,
                              void* d_out, int out_size, void* d_ws, size_t ws_size,
                              hipStream_t stream)
{
    const float* query   = (const float*)d_in[0];
    const float* key     = (const float*)d_in[1];
    const float* value   = (const float*)d_in[2];
    const float* q_boxes = (const float*)d_in[3];
    const float* k_boxes = (const float*)d_in[4];
    const float* Wq      = (const float*)d_in[5];
    const float* Wk      = (const float*)d_in[6];
    const float* Wv      = (const float*)d_in[7];
    const float* pos_w   = (const float*)d_in[8];
    const float* pos_b   = (const float*)d_in[9];

    unsigned short* u = (unsigned short*)d_ws;
    unsigned short* xq  = u;                      // 1048576
    unsigned short* xk  = xq + 1048576;
    unsigned short* xv  = xk + 1048576;
    unsigned short* wqb = xv + 1048576;           // 65536 each
    unsigned short* wkb = wqb + 65536;
    unsigned short* wvb = wkb + 65536;
    unsigned short* qbf = wvb + 65536;            // 1048576 [bh][n][d]
    unsigned short* kbf = qbf + 1048576;
    unsigned short* vtb = kbf + 1048576;          // [bh][d][n]
    unsigned short* bias = vtb + 1048576;         // 8388608

    float* out  = (float*)d_out;                  // [N,B,C]
    float* attn = out + (size_t)PN * PB * PC;     // [B,H,N,N]

    cvt_kernel<<<dim3(3264), 256, 0, stream>>>(query, key, value, Wq, Wk, Wv,
                                               xq, xk, xv, wqb, wkb, wvb);
    proj_mfma<<<dim3(64, 4, 3), 256, 0, stream>>>(xq, xk, xv, wqb, wkb, wvb,
                                                  qbf, kbf, vtb);
    norm_kernel<<<dim3(256), 256, 0, stream>>>(qbf, kbf);
    bias_kernel<<<dim3(4096), 256, 0, stream>>>(q_boxes, k_boxes, pos_w, pos_b, bias);
    attn_kernel<<<dim3(32, 32), 512, 0, stream>>>(qbf, kbf, vtb, bias, out, attn);
}

// Round 8
// 233.176 us; speedup vs baseline: 2.3032x; 1.0098x over previous
//
#include <hip/hip_runtime.h>
#include <hip/hip_bf16.h>
#include <math.h>

#define PN 1024
#define PB 4
#define PC 256
#define PH 8
#define PD 32

typedef __attribute__((ext_vector_type(8))) short bf16x8;
typedef __attribute__((ext_vector_type(4))) float f32x4;

__device__ __forceinline__ unsigned short f2b(float f) {
    unsigned int u = __builtin_bit_cast(unsigned int, f);
    unsigned int r = (u + 0x7fffu + ((u >> 16) & 1u)) >> 16;
    return (unsigned short)r;
}
__device__ __forceinline__ float b2f(unsigned short u) {
    return __builtin_bit_cast(float, ((unsigned int)u) << 16);
}
// load 8 consecutive f32, convert to bf16x8 fragment
__device__ __forceinline__ bf16x8 ldf8(const float* p) {
    float4 u0 = ((const float4*)p)[0];
    float4 u1 = ((const float4*)p)[1];
    bf16x8 r;
    r[0] = (short)f2b(u0.x); r[1] = (short)f2b(u0.y);
    r[2] = (short)f2b(u0.z); r[3] = (short)f2b(u0.w);
    r[4] = (short)f2b(u1.x); r[5] = (short)f2b(u1.y);
    r[6] = (short)f2b(u1.z); r[7] = (short)f2b(u1.w);
    return r;
}

// ---------------------------------------------------------------------------
// Kernel 1: projection via MFMA, f32 inputs converted in-register.
// Y = X @ W^T  (X: 4096x256 f32, W: 256x256 f32)
// z=0: q -> qb [bh][n][d] bf16, cosine-NORMALIZED in epilogue
// z=1: k -> kb [bh][n][d] bf16, cosine-NORMALIZED in epilogue
// z=2: v -> vt [bh][d][n] bf16 (transposed, unnormalized)
// ---------------------------------------------------------------------------
__global__ __launch_bounds__(256) void proj_mfma(
    const float* __restrict__ xq, const float* __restrict__ xk, const float* __restrict__ xv,
    const float* __restrict__ wq, const float* __restrict__ wk, const float* __restrict__ wv,
    unsigned short* __restrict__ qb, unsigned short* __restrict__ kb, unsigned short* __restrict__ vt)
{
    const int z = blockIdx.z;
    const float* X = (z == 0) ? xq : (z == 1) ? xk : xv;
    const float* W = (z == 0) ? wq : (z == 1) ? wk : wv;

    const int row0 = blockIdx.x * 64, col0 = blockIdx.y * 64;
    const int tid = threadIdx.x;
    const int w = tid >> 6, l = tid & 63;
    const int l15 = l & 15, lg = l >> 4;
    const int wm = w >> 1, wn = w & 1;

    f32x4 acc[2][2];
    #pragma unroll
    for (int a = 0; a < 2; a++)
        #pragma unroll
        for (int b = 0; b < 2; b++) acc[a][b] = (f32x4){0.f, 0.f, 0.f, 0.f};

    #pragma unroll
    for (int ks = 0; ks < 8; ks++) {
        int koff = ks * 32 + lg * 8;
        bf16x8 a0 = ldf8(X + (size_t)(row0 + wm * 32 + l15) * 256 + koff);
        bf16x8 a1 = ldf8(X + (size_t)(row0 + wm * 32 + 16 + l15) * 256 + koff);
        bf16x8 b0 = ldf8(W + (size_t)(col0 + wn * 32 + l15) * 256 + koff);
        bf16x8 b1 = ldf8(W + (size_t)(col0 + wn * 32 + 16 + l15) * 256 + koff);
        acc[0][0] = __builtin_amdgcn_mfma_f32_16x16x32_bf16(a0, b0, acc[0][0], 0, 0, 0);
        acc[0][1] = __builtin_amdgcn_mfma_f32_16x16x32_bf16(a0, b1, acc[0][1], 0, 0, 0);
        acc[1][0] = __builtin_amdgcn_mfma_f32_16x16x32_bf16(a1, b0, acc[1][0], 0, 0, 0);
        acc[1][1] = __builtin_amdgcn_mfma_f32_16x16x32_bf16(a1, b1, acc[1][1], 0, 0, 0);
    }

    // cosine normalization for q/k: each (as,r) row's 32-col head segment
    // [col0+wn*32, +32) is held by 16 lanes (l15) x 2 bs. shfl over l15 bits.
    if (z < 2) {
        #pragma unroll
        for (int as = 0; as < 2; as++) {
            #pragma unroll
            for (int r = 0; r < 4; r++) {
                float ss = acc[as][0][r] * acc[as][0][r] + acc[as][1][r] * acc[as][1][r];
                ss += __shfl_xor(ss, 1);
                ss += __shfl_xor(ss, 2);
                ss += __shfl_xor(ss, 4);
                ss += __shfl_xor(ss, 8);
                float inv = rsqrtf(ss);
                acc[as][0][r] *= inv;
                acc[as][1][r] *= inv;
            }
        }
    }

    #pragma unroll
    for (int as = 0; as < 2; as++) {
        #pragma unroll
        for (int bs = 0; bs < 2; bs++) {
            #pragma unroll
            for (int r = 0; r < 4; r++) {
                int Xrow = row0 + wm * 32 + as * 16 + lg * 4 + r;
                int c = col0 + wn * 32 + bs * 16 + l15;
                int n = Xrow >> 2, bb = Xrow & 3, hh = c >> 5, dd = c & 31;
                unsigned short val = f2b(acc[as][bs][r]);
                if (z == 0)      qb[((size_t)((bb * 8 + hh) * 1024 + n)) * 32 + dd] = val;
                else if (z == 1) kb[((size_t)((bb * 8 + hh) * 1024 + n)) * 32 + dd] = val;
                else             vt[((size_t)((bb * 8 + hh) * 32 + dd)) * 1024 + n] = val;
            }
        }
    }
}

// ---------------------------------------------------------------------------
// Kernel 2: position bias [H,N,N] -> bf16 (hw sin/cos; args bounded)
// ---------------------------------------------------------------------------
__global__ __launch_bounds__(256) void bias_kernel(
    const float* __restrict__ qbx, const float* __restrict__ kbx,
    const float* __restrict__ pw, const float* __restrict__ pb,
    unsigned short* __restrict__ biasb)
{
    __shared__ float4 pwS[128];
    __shared__ float pbS[8];
    int tid = threadIdx.x;
    if (tid < 128) pwS[tid] = ((const float4*)pw)[tid];
    if (tid < 8) pbS[tid] = pb[tid];
    __syncthreads();

    int idx = blockIdx.x * 256 + tid;
    int n = idx >> 10, m = idx & 1023;

    float4 qx = ((const float4*)qbx)[n];
    float4 kx = ((const float4*)kbx)[m];

    float cx = 0.5f * (qx.x + qx.z), cy = 0.5f * (qx.y + qx.w);
    float w  = qx.z - qx.x + 1.0f,   hh = qx.w - qx.y + 1.0f;
    float cxr = 0.5f * (kx.x + kx.z), cyr = 0.5f * (kx.y + kx.w);
    float wr  = kx.z - kx.x + 1.0f,   hr  = kx.w - kx.y + 1.0f;

    float pm[4];
    pm[0] = __logf(fabsf((cx - cxr) / w) + 1e-3f);
    pm[1] = __logf(fabsf((cy - cyr) / hh) + 1e-3f);
    pm[2] = __logf(w / wr);
    pm[3] = __logf(hh / hr);

    const float inv[8] = {100.f, 42.1696503f, 17.7827941f, 7.49894209f,
                          3.16227766f, 1.33352143f, 0.562341325f, 0.237137371f};

    float emb[64];
    #pragma unroll
    for (int p = 0; p < 4; p++) {
        #pragma unroll
        for (int i = 0; i < 8; i++) {
            float a = pm[p] * inv[i];
            emb[p * 16 + i]     = __sinf(a);
            emb[p * 16 + 8 + i] = __cosf(a);
        }
    }

    #pragma unroll
    for (int h = 0; h < PH; h++) {
        float acc = pbS[h];
        #pragma unroll
        for (int c4 = 0; c4 < 16; c4++) {
            float4 w4 = pwS[h * 16 + c4];
            acc += emb[c4 * 4 + 0] * w4.x + emb[c4 * 4 + 1] * w4.y
                 + emb[c4 * 4 + 2] * w4.z + emb[c4 * 4 + 3] * w4.w;
        }
        float bv = __logf(fmaxf(acc, 0.f) + 1e-6f);
        biasb[((size_t)(h * 1024 + n)) * 1024 + m] = f2b(bv);
    }
}

// ---------------------------------------------------------------------------
// Kernel 3: fused attention. Block: 16 queries x 1024 keys of one (b,h).
// 512 threads = 8 waves. LDS ~42 KB -> 3 blocks/CU by LDS.
// ---------------------------------------------------------------------------
#define SBS 1032   // bf16 elems per Sb row (2064 B, 16B-aligned rows)

__global__ __launch_bounds__(512, 4) void attn_kernel(
    const unsigned short* __restrict__ qb, const unsigned short* __restrict__ kb,
    const unsigned short* __restrict__ vt, const unsigned short* __restrict__ biasb,
    float* __restrict__ out, float* __restrict__ attn_out)
{
    __shared__ unsigned short Sb[16][SBS];        // 33024 B
    __shared__ float part[8][16][17];             // 8704 B

    const int bh = blockIdx.y;
    const int b = bh >> 3, h = bh & 7;
    const int n0 = blockIdx.x * 16;
    const int tid = threadIdx.x;
    const int w = tid >> 6, l = tid & 63;
    const int l15 = l & 15, lg = l >> 4;

    // ---- QK^T: wave w covers keys [w*128, w*128+128) = 8 MFMAs ----
    {
        const int qrow = n0 + l15;
        bf16x8 aq = *(const bf16x8*)(qb + ((size_t)(bh << 10) + qrow) * 32 + lg * 8);
        #pragma unroll
        for (int t = 0; t < 8; ++t) {
            int key = w * 128 + t * 16 + l15;
            bf16x8 bk = *(const bf16x8*)(kb + ((size_t)(bh << 10) + key) * 32 + lg * 8);
            f32x4 acc = (f32x4){0.f, 0.f, 0.f, 0.f};
            acc = __builtin_amdgcn_mfma_f32_16x16x32_bf16(aq, bk, acc, 0, 0, 0);
            #pragma unroll
            for (int r = 0; r < 4; ++r)
                Sb[lg * 4 + r][key] = f2b(acc[r]);
        }
    }
    __syncthreads();

    // ---- softmax + bias + attn write + P(bf16) back to LDS: 2 rows/wave ----
    {
        #pragma unroll
        for (int rr = 0; rr < 2; ++rr) {
            int r = w * 2 + rr;
            float s[16];
            #pragma unroll
            for (int i = 0; i < 16; ++i) s[i] = b2f(Sb[r][l + 64 * i]);
            float mx = s[0];
            #pragma unroll
            for (int i = 1; i < 16; ++i) mx = fmaxf(mx, s[i]);
            #pragma unroll
            for (int off = 32; off > 0; off >>= 1) mx = fmaxf(mx, __shfl_xor(mx, off));
            float e[16], sum = 0.f;
            #pragma unroll
            for (int i = 0; i < 16; ++i) { e[i] = __expf(s[i] - mx); sum += e[i]; }
            #pragma unroll
            for (int off = 32; off > 0; off >>= 1) sum += __shfl_xor(sum, off);
            float invs = 1.f / sum;

            const unsigned short* brow = biasb + ((size_t)(h * 1024 + n0 + r)) * 1024;
            float* arow = attn_out + ((size_t)(bh * 1024 + n0 + r)) * 1024;
            #pragma unroll
            for (int i = 0; i < 16; ++i) {
                int m = l + 64 * i;
                float a = e[i] * invs + b2f(brow[m]);
                arow[m] = a;
                Sb[r][m] = f2b(a);
            }
        }
    }
    __syncthreads();

    // ---- PV: wave = (ds = w>>2, kh = w&3); m-range kh*256..+256 ----
    {
        const int ds = w >> 2, kh = w & 3;
        f32x4 acc = (f32x4){0.f, 0.f, 0.f, 0.f};
        const unsigned short* vrow = vt + ((size_t)(bh * 32 + ds * 16 + l15) << 10);
        const unsigned short* srow = &Sb[l15][0];
        #pragma unroll
        for (int st = 0; st < 8; ++st) {
            int m0 = kh * 256 + st * 32 + lg * 8;
            bf16x8 ap = *(const bf16x8*)(srow + m0);
            bf16x8 bv = *(const bf16x8*)(vrow + m0);
            acc = __builtin_amdgcn_mfma_f32_16x16x32_bf16(ap, bv, acc, 0, 0, 0);
        }
        #pragma unroll
        for (int r = 0; r < 4; ++r) part[w][lg * 4 + r][l15] = acc[r];
    }
    __syncthreads();

    // ---- reduce k-quarters, write out [n][b][c] ----
    {
        int q = tid >> 5, d = tid & 31;
        int ds = d >> 4, d15 = d & 15;
        float v = part[ds * 4 + 0][q][d15] + part[ds * 4 + 1][q][d15]
                + part[ds * 4 + 2][q][d15] + part[ds * 4 + 3][q][d15];
        out[((size_t)(n0 + q) * PB + b) * PC + h * PD + d] = v;
    }
}

// ---------------------------------------------------------------------------
extern "C" void kernel_launch(void* const* d_in, const int* in_sizes, int n_in,
                              void* d_out, int out_size, void* d_ws, size_t ws_size,
                              hipStream_t stream)
{
    const float* query   = (const float*)d_in[0];
    const float* key     = (const float*)d_in[1];
    const float* value   = (const float*)d_in[2];
    const float* q_boxes = (const float*)d_in[3];
    const float* k_boxes = (const float*)d_in[4];
    const float* Wq      = (const float*)d_in[5];
    const float* Wk      = (const float*)d_in[6];
    const float* Wv      = (const float*)d_in[7];
    const float* pos_w   = (const float*)d_in[8];
    const float* pos_b   = (const float*)d_in[9];

    unsigned short* u = (unsigned short*)d_ws;
    unsigned short* qbf  = u;                     // 1048576 [bh][n][d] normalized
    unsigned short* kbf  = qbf + 1048576;         // 1048576 [bh][n][d] normalized
    unsigned short* vtb  = kbf + 1048576;         // 1048576 [bh][d][n]
    unsigned short* bias = vtb + 1048576;         // 8388608 [h][n][m]

    float* out  = (float*)d_out;                  // [N,B,C]
    float* attn = out + (size_t)PN * PB * PC;     // [B,H,N,N]

    proj_mfma<<<dim3(64, 4, 3), 256, 0, stream>>>(query, key, value, Wq, Wk, Wv,
                                                  qbf, kbf, vtb);
    bias_kernel<<<dim3(4096), 256, 0, stream>>>(q_boxes, k_boxes, pos_w, pos_b, bias);
    attn_kernel<<<dim3(64, 32), 512, 0, stream>>>(qbf, kbf, vtb, bias, out, attn);
}